// Round 7
// baseline (119.177 us; speedup 1.0000x reference)
//
#include <hip/hip_runtime.h>

// Chamfer distance, B=16 clouds x N=4096 x D=3, fp32, via bf16-split MFMA.
// S_ij = d(x_i, y_j) computed by ONE v_mfma_f32_32x32x16_bf16 dot (K=16):
//   A_i = [xh0..2, xl0..2, xh0..2, x2h, x2l, 1, 1, xl0..2]
//   B_j = [-2yh0..2, -2yh0..2, -2yl0..2, 1, 1, y2h, y2l, -2yl0..2]
//   sum_k A_ik B_jk = x^2 + y^2 - 2(xh+xl).(yh+yl)  (abs err <~7e-4)
// One S serves both directions: row-mins -> cham_x, col-mins -> cham_y.
// R6 post-mortem: VALU(27us)+LDS(20us) pipes refused to overlap; MFMA moves
// the pairwise work to the matrix pipe (262k MFMAs ~ 1us); epilogue mins are
// 16 min3 + 2 trees per 64 d-values.

namespace {

constexpr int kB = 16;
constexpr int kN = 4096;
constexpr int kPlane = kB * kN;
constexpr float kScale = 1.0f / (float)(kB * kN);

typedef short bf16x8 __attribute__((ext_vector_type(8)));
typedef float f32x16 __attribute__((ext_vector_type(16)));
typedef unsigned short u16;

__device__ inline u16 bf16_rn(float f) {
  union { float f; unsigned u; } v; v.f = f;
  unsigned r = v.u + 0x7fffu + ((v.u >> 16) & 1u);
  return (u16)(r >> 16);
}
__device__ inline float bf16_f(u16 h) {
  union { unsigned u; float f; } v; v.u = (unsigned)h << 16;
  return v.f;
}
__device__ inline unsigned pk2(u16 lo, u16 hi) {
  return (unsigned)lo | ((unsigned)hi << 16);
}

__global__ void init_out(float* out) { out[0] = 0.0f; }

// Build K=16 bf16 rows for A (from pred) and B (from target); zero out[0].
__global__ __launch_bounds__(256) void cd_prep(
    const float* __restrict__ pred, const float* __restrict__ targ,
    u16* __restrict__ Ab, u16* __restrict__ Bb, float* __restrict__ out) {
  const int p = blockIdx.x * 256 + threadIdx.x;   // 0..kPlane-1
  if (p == 0) out[0] = 0.0f;
  const u16 one = 0x3F80;
  {  // A row from pred point p
    const float a = pred[3 * p], c = pred[3 * p + 1], d = pred[3 * p + 2];
    const u16 ah = bf16_rn(a), ch = bf16_rn(c), dh = bf16_rn(d);
    const u16 al = bf16_rn(a - bf16_f(ah));
    const u16 cl = bf16_rn(c - bf16_f(ch));
    const u16 dl = bf16_rn(d - bf16_f(dh));
    const float s2 = fmaf(a, a, fmaf(c, c, d * d));
    const u16 s2h = bf16_rn(s2);
    const u16 s2l = bf16_rn(s2 - bf16_f(s2h));
    // k: 0-2 xh, 3-5 xl, 6-8 xh, 9 x2h, 10 x2l, 11 one, 12 one, 13-15 xl
    uint4 w0, w1;
    w0.x = pk2(ah, ch); w0.y = pk2(dh, al); w0.z = pk2(cl, dl); w0.w = pk2(ah, ch);
    w1.x = pk2(dh, s2h); w1.y = pk2(s2l, one); w1.z = pk2(one, al); w1.w = pk2(cl, dl);
    uint4* dst = reinterpret_cast<uint4*>(Ab + (size_t)p * 16);
    dst[0] = w0; dst[1] = w1;
  }
  {  // B row from target point p
    const float a = targ[3 * p], c = targ[3 * p + 1], d = targ[3 * p + 2];
    const u16 ah0 = bf16_rn(a), ch0 = bf16_rn(c), dh0 = bf16_rn(d);
    const u16 ah = bf16_rn(-2.0f * bf16_f(ah0));   // exact scale by -2
    const u16 ch = bf16_rn(-2.0f * bf16_f(ch0));
    const u16 dh = bf16_rn(-2.0f * bf16_f(dh0));
    const u16 al = bf16_rn(-2.0f * bf16_f(bf16_rn(a - bf16_f(ah0))));
    const u16 cl = bf16_rn(-2.0f * bf16_f(bf16_rn(c - bf16_f(ch0))));
    const u16 dl = bf16_rn(-2.0f * bf16_f(bf16_rn(d - bf16_f(dh0))));
    const float s2 = fmaf(a, a, fmaf(c, c, d * d));
    const u16 s2h = bf16_rn(s2);
    const u16 s2l = bf16_rn(s2 - bf16_f(s2h));
    // k: 0-2 -2yh, 3-5 -2yh, 6-8 -2yl, 9 one, 10 one, 11 y2h, 12 y2l, 13-15 -2yl
    uint4 w0, w1;
    w0.x = pk2(ah, ch); w0.y = pk2(dh, ah); w0.z = pk2(ch, dh); w0.w = pk2(al, cl);
    w1.x = pk2(dl, one); w1.y = pk2(one, s2h); w1.z = pk2(s2l, al); w1.w = pk2(cl, dl);
    uint4* dst = reinterpret_cast<uint4*>(Bb + (size_t)p * 16);
    dst[0] = w0; dst[1] = w1;
  }
}

// Block = 4 waves; wave owns 32 rows (i), scans all 4096 j in 2-tile steps.
// Row-mins finish in-wave (butterfly) -> atomicAdd. Col-mins per wave go to
// LDS (private region), block-combined -> colpart[cloud][chunk][4096].
__global__ __launch_bounds__(256) void cd_mfma(
    const u16* __restrict__ Ab, const u16* __restrict__ Bb,
    float* __restrict__ colpart, float* __restrict__ out) {
  __shared__ float clds[4 * kN];     // 64 KB: per-wave col-min regions

  const int t = threadIdx.x;
  const int w = t >> 6, lane = t & 63;
  const int half = lane >> 5, l31 = lane & 31;
  const int chunk = blockIdx.x;      // 0..31 -> 128 rows per block
  const int cloud = blockIdx.y;      // 0..15

  // A fragment: lane holds A[i = iband+l31][k = half*8 .. +7]
  const int arow = cloud * kN + chunk * 128 + w * 32 + l31;
  const bf16x8 afrag = *(const bf16x8*)(Ab + (size_t)arow * 16 + half * 8);

  f32x16 zacc;
#pragma unroll
  for (int r = 0; r < 16; ++r) zacc[r] = 0.0f;
  float rmin[16];
#pragma unroll
  for (int r = 0; r < 16; ++r) rmin[r] = 1e30f;

  const u16* bbase = Bb + (size_t)cloud * kN * 16;
  constexpr int NT = kN / 64;        // 64 iterations, 64 j per iteration
  const int jcol = l31 * 16 + half * 8;
  bf16x8 b0 = *(const bf16x8*)(bbase + jcol);
  bf16x8 b1 = *(const bf16x8*)(bbase + 32 * 16 + jcol);
  for (int jt = 0; jt < NT; ++jt) {
    const int nx = ((jt + 1) & (NT - 1)) * 64 * 16;
    const bf16x8 n0 = *(const bf16x8*)(bbase + nx + jcol);
    const bf16x8 n1 = *(const bf16x8*)(bbase + nx + 32 * 16 + jcol);
    const f32x16 s0 = __builtin_amdgcn_mfma_f32_32x32x16_bf16(afrag, b0, zacc, 0, 0, 0);
    const f32x16 s1 = __builtin_amdgcn_mfma_f32_32x32x16_bf16(afrag, b1, zacc, 0, 0, 0);
    float cm0 = s0[0], cm1 = s1[0];
#pragma unroll
    for (int r = 1; r < 16; ++r) { cm0 = fminf(cm0, s0[r]); cm1 = fminf(cm1, s1[r]); }
#pragma unroll
    for (int r = 0; r < 16; ++r) rmin[r] = fminf(rmin[r], fminf(s0[r], s1[r]));
    cm0 = fminf(cm0, __shfl_xor(cm0, 32, 64));   // join the two row-halves
    cm1 = fminf(cm1, __shfl_xor(cm1, 32, 64));
    if (half == 0) {
      clds[w * kN + jt * 64 + l31] = cm0;
      clds[w * kN + jt * 64 + 32 + l31] = cm1;
    }
    b0 = n0; b1 = n1;
  }

  // Row-mins: butterfly min across the 32 lanes sharing this half's rows.
#pragma unroll
  for (int st = 1; st < 32; st <<= 1) {
#pragma unroll
    for (int r = 0; r < 16; ++r)
      rmin[r] = fminf(rmin[r], __shfl_xor(rmin[r], st, 64));
  }
  if (l31 == 0) {   // lanes 0 and 32: each holds its half's 16 row-mins
    float s = 0.0f;
#pragma unroll
    for (int r = 0; r < 16; ++r) s += rmin[r];
    atomicAdd(out, s * kScale);
  }

  __syncthreads();
  for (int j = t; j < kN; j += 256) {
    const float m = fminf(fminf(clds[j], clds[kN + j]),
                          fminf(clds[2 * kN + j], clds[3 * kN + j]));
    colpart[((size_t)cloud * 32 + chunk) * kN + j] = m;
  }
}

// Per (cloud, j): min over 32 chunk partials; block-sum -> atomicAdd.
__global__ __launch_bounds__(256) void cd_colreduce(
    const float* __restrict__ colpart, float* __restrict__ out) {
  const int u = blockIdx.x * 256 + threadIdx.x;   // 0..kPlane-1
  const int cloud = u >> 12, j = u & (kN - 1);
  const float* p = colpart + (size_t)cloud * 32 * kN + j;
  float m = 1e30f;
#pragma unroll 8
  for (int c = 0; c < 32; ++c) m = fminf(m, p[(size_t)c * kN]);
  float s = m;
  for (int o = 32; o > 0; o >>= 1) s += __shfl_down(s, o, 64);
  __shared__ float wsum[4];
  const int lane = threadIdx.x & 63, wv = threadIdx.x >> 6;
  if (lane == 0) wsum[wv] = s;
  __syncthreads();
  if (threadIdx.x == 0)
    atomicAdd(out, (wsum[0] + wsum[1] + wsum[2] + wsum[3]) * kScale);
}

// ---------- fallback (small ws): R5-style pk_fma direct kernel ----------
template <int KX>
__global__ __launch_bounds__(256) void chamfer_direct(
    const float* __restrict__ pred, const float* __restrict__ targ,
    float* __restrict__ out) {
  __shared__ float4 tA[128], tB[128];
  const int t = threadIdx.x;
  const int xb = blockIdx.x, b = blockIdx.y, dir = blockIdx.z;
  const float* __restrict__ X = dir ? targ : pred;
  const float* __restrict__ Y = dir ? pred : targ;
  float2 xx2[KX], xy2[KX], xz2[KX];
  float x2[KX], mn[KX];
  const int ibase = b * kN + xb * (256 * KX) + t;
#pragma unroll
  for (int k = 0; k < KX; ++k) {
    const int i = ibase + k * 256;
    const float a = X[3 * i], c = X[3 * i + 1], d = X[3 * i + 2];
    x2[k] = fmaf(a, a, fmaf(c, c, d * d));
    xx2[k] = make_float2(-2.0f * a, -2.0f * a);
    xy2[k] = make_float2(-2.0f * c, -2.0f * c);
    xz2[k] = make_float2(-2.0f * d, -2.0f * d);
    mn[k] = 1e30f;
  }
  for (int t0 = 0; t0 < kN; t0 += 256) {
    __syncthreads();
    if (t < 128) {
      const int j0 = 3 * (b * kN + t0 + 2 * t);
      const float a0 = Y[j0], c0 = Y[j0 + 1], d0 = Y[j0 + 2];
      const float a1 = Y[j0 + 3], c1 = Y[j0 + 4], d1 = Y[j0 + 5];
      tA[t] = make_float4(a0, a1, c0, c1);
      tB[t] = make_float4(d0, d1, fmaf(a0, a0, fmaf(c0, c0, d0 * d0)),
                          fmaf(a1, a1, fmaf(c1, c1, d1 * d1)));
    }
    __syncthreads();
    for (int jj = 0; jj < 128; ++jj) {
      const float4 qa = tA[jj], qb = tB[jj];
      const float2 qx = make_float2(qa.x, qa.y), qy = make_float2(qa.z, qa.w);
      const float2 qz = make_float2(qb.x, qb.y), qw = make_float2(qb.z, qb.w);
#pragma unroll
      for (int k = 0; k < KX; ++k) {
        float2 acc;
        asm("v_pk_fma_f32 %0, %1, %2, %3\n\t"
            "v_pk_fma_f32 %0, %4, %5, %0\n\t"
            "v_pk_fma_f32 %0, %6, %7, %0"
            : "=&v"(acc)
            : "v"(xz2[k]), "v"(qz), "v"(qw), "v"(xy2[k]), "v"(qy),
              "v"(xx2[k]), "v"(qx));
        asm("v_min3_f32 %0, %0, %1, %2" : "+v"(mn[k]) : "v"(acc.x), "v"(acc.y));
      }
    }
  }
  float s = 0.0f;
#pragma unroll
  for (int k = 0; k < KX; ++k) s += x2[k] + mn[k];
  for (int o = 32; o > 0; o >>= 1) s += __shfl_down(s, o, 64);
  __shared__ float wsum[4];
  const int lane = t & 63, wv = t >> 6;
  if (lane == 0) wsum[wv] = s;
  __syncthreads();
  if (t == 0)
    atomicAdd(out, (wsum[0] + wsum[1] + wsum[2] + wsum[3]) * kScale);
}

}  // namespace

extern "C" void kernel_launch(void* const* d_in, const int* in_sizes, int n_in,
                              void* d_out, int out_size, void* d_ws,
                              size_t ws_size, hipStream_t stream) {
  const float* pred = (const float*)d_in[0];
  const float* targ = (const float*)d_in[1];
  float* out = (float*)d_out;

  const size_t needA = (size_t)kPlane * 16 * sizeof(u16);       // 2 MB
  const size_t needCol = (size_t)kB * 32 * kN * sizeof(float);  // 8 MB
  if (ws_size >= 2 * needA + needCol) {                         // 12 MB
    u16* Ab = (u16*)d_ws;
    u16* Bb = (u16*)((char*)d_ws + needA);
    float* colpart = (float*)((char*)d_ws + 2 * needA);
    cd_prep<<<dim3(kPlane / 256), 256, 0, stream>>>(pred, targ, Ab, Bb, out);
    cd_mfma<<<dim3(32, kB), 256, 0, stream>>>(Ab, Bb, colpart, out);
    cd_colreduce<<<dim3(kPlane / 256), 256, 0, stream>>>(colpart, out);
  } else {
    init_out<<<dim3(1), dim3(1), 0, stream>>>(out);
    constexpr int KX = 8;
    dim3 grid(kN / (256 * KX), kB, 2);
    chamfer_direct<KX><<<grid, 256, 0, stream>>>(pred, targ, out);
  }
}

// Round 8
// 96.047 us; speedup vs baseline: 1.2408x; 1.2408x over previous
//
#include <hip/hip_runtime.h>

// Chamfer distance, B=16 clouds x N=4096 x D=3, fp32, via bf16-split MFMA.
// S_ij = d(x_i, y_j) computed by ONE v_mfma_f32_32x32x16_bf16 dot (K=16):
//   A_i = [xh0..2, xl0..2, xh0..2, x2h, x2l, 1, 1, xl0..2]
//   B_j = [-2yh0..2, -2yh0..2, -2yl0..2, 1, 1, y2h, y2l, -2yl0..2]
//   sum_k A_ik B_jk = x^2 + y^2 - 2(xh+xl).(yh+yl)  (abs err <~7e-4)
// One S serves both directions: row-mins -> cham_x, col-mins -> cham_y.
// R8: R7 was latency-bound (occupancy 14%, VALUBusy 32%, 64KB LDS -> 2
// blocks/CU). Slice j 4-way: 2048 blocks, 16KB LDS, ~20 waves/CU. Row-mins
// now slice-partial -> rowpart (1MB); one reduce kernel folds rows+cols.

namespace {

constexpr int kB = 16;
constexpr int kN = 4096;
constexpr int kPlane = kB * kN;
constexpr int kJS = 4;                    // j-slices
constexpr int kJSL = kN / kJS;            // 1024 j per slice
constexpr float kScale = 1.0f / (float)(kB * kN);

typedef short bf16x8 __attribute__((ext_vector_type(8)));
typedef float f32x16 __attribute__((ext_vector_type(16)));
typedef unsigned short u16;

__device__ inline u16 bf16_rn(float f) {
  union { float f; unsigned u; } v; v.f = f;
  unsigned r = v.u + 0x7fffu + ((v.u >> 16) & 1u);
  return (u16)(r >> 16);
}
__device__ inline float bf16_f(u16 h) {
  union { unsigned u; float f; } v; v.u = (unsigned)h << 16;
  return v.f;
}
__device__ inline unsigned pk2(u16 lo, u16 hi) {
  return (unsigned)lo | ((unsigned)hi << 16);
}

__global__ void init_out(float* out) { out[0] = 0.0f; }

// Build K=16 bf16 rows for A (from pred) and B (from target); zero out[0].
__global__ __launch_bounds__(256) void cd_prep(
    const float* __restrict__ pred, const float* __restrict__ targ,
    u16* __restrict__ Ab, u16* __restrict__ Bb, float* __restrict__ out) {
  const int p = blockIdx.x * 256 + threadIdx.x;   // 0..kPlane-1
  if (p == 0) out[0] = 0.0f;
  const u16 one = 0x3F80;
  {  // A row from pred point p
    const float a = pred[3 * p], c = pred[3 * p + 1], d = pred[3 * p + 2];
    const u16 ah = bf16_rn(a), ch = bf16_rn(c), dh = bf16_rn(d);
    const u16 al = bf16_rn(a - bf16_f(ah));
    const u16 cl = bf16_rn(c - bf16_f(ch));
    const u16 dl = bf16_rn(d - bf16_f(dh));
    const float s2 = fmaf(a, a, fmaf(c, c, d * d));
    const u16 s2h = bf16_rn(s2);
    const u16 s2l = bf16_rn(s2 - bf16_f(s2h));
    // k: 0-2 xh, 3-5 xl, 6-8 xh, 9 x2h, 10 x2l, 11 one, 12 one, 13-15 xl
    uint4 w0, w1;
    w0.x = pk2(ah, ch); w0.y = pk2(dh, al); w0.z = pk2(cl, dl); w0.w = pk2(ah, ch);
    w1.x = pk2(dh, s2h); w1.y = pk2(s2l, one); w1.z = pk2(one, al); w1.w = pk2(cl, dl);
    uint4* dst = reinterpret_cast<uint4*>(Ab + (size_t)p * 16);
    dst[0] = w0; dst[1] = w1;
  }
  {  // B row from target point p
    const float a = targ[3 * p], c = targ[3 * p + 1], d = targ[3 * p + 2];
    const u16 ah0 = bf16_rn(a), ch0 = bf16_rn(c), dh0 = bf16_rn(d);
    const u16 ah = bf16_rn(-2.0f * bf16_f(ah0));   // exact scale by -2
    const u16 ch = bf16_rn(-2.0f * bf16_f(ch0));
    const u16 dh = bf16_rn(-2.0f * bf16_f(dh0));
    const u16 al = bf16_rn(-2.0f * bf16_f(bf16_rn(a - bf16_f(ah0))));
    const u16 cl = bf16_rn(-2.0f * bf16_f(bf16_rn(c - bf16_f(ch0))));
    const u16 dl = bf16_rn(-2.0f * bf16_f(bf16_rn(d - bf16_f(dh0))));
    const float s2 = fmaf(a, a, fmaf(c, c, d * d));
    const u16 s2h = bf16_rn(s2);
    const u16 s2l = bf16_rn(s2 - bf16_f(s2h));
    // k: 0-2 -2yh, 3-5 -2yh, 6-8 -2yl, 9 one, 10 one, 11 y2h, 12 y2l, 13-15 -2yl
    uint4 w0, w1;
    w0.x = pk2(ah, ch); w0.y = pk2(dh, ah); w0.z = pk2(ch, dh); w0.w = pk2(al, cl);
    w1.x = pk2(dl, one); w1.y = pk2(one, s2h); w1.z = pk2(s2l, al); w1.w = pk2(cl, dl);
    uint4* dst = reinterpret_cast<uint4*>(Bb + (size_t)p * 16);
    dst[0] = w0; dst[1] = w1;
  }
}

// Block = 4 waves; wave owns 32 rows (i), scans its 1024-j slice.
// C/D layout (32x32x16): col=lane&31, row=(reg&3)+8*(reg>>2)+4*(lane>>5).
// Col-mins per wave -> LDS region, block-combined -> colpart[cloud][chunk][j].
// Row-mins (slice-partial) -> butterfly over 32 lanes -> rowpart.
__global__ __launch_bounds__(256) void cd_mfma(
    const u16* __restrict__ Ab, const u16* __restrict__ Bb,
    float* __restrict__ colpart, float* __restrict__ rowpart) {
  __shared__ float clds[4 * kJSL];   // 16 KB: per-wave col-min regions

  const int t = threadIdx.x;
  const int w = t >> 6, lane = t & 63;
  const int half = lane >> 5, l31 = lane & 31;
  const int chunk = blockIdx.x;      // 0..31 -> 128 rows per block
  const int cloud = blockIdx.y;      // 0..15
  const int slice = blockIdx.z;      // 0..kJS-1

  // A fragment: lane holds A[i = band+l31][k = half*8 .. +7]
  const int arow = cloud * kN + chunk * 128 + w * 32 + l31;
  const bf16x8 afrag = *(const bf16x8*)(Ab + (size_t)arow * 16 + half * 8);

  f32x16 zacc;
#pragma unroll
  for (int r = 0; r < 16; ++r) zacc[r] = 0.0f;
  float rmin[16];
#pragma unroll
  for (int r = 0; r < 16; ++r) rmin[r] = 1e30f;

  const u16* bbase = Bb + ((size_t)cloud * kN + slice * kJSL) * 16;
  constexpr int NT = kJSL / 64;      // 16 iterations, 64 j per iteration
  const int jcol = l31 * 16 + half * 8;
  bf16x8 b0 = *(const bf16x8*)(bbase + jcol);
  bf16x8 b1 = *(const bf16x8*)(bbase + 32 * 16 + jcol);
  for (int jt = 0; jt < NT; ++jt) {
    const int nx = ((jt + 1) & (NT - 1)) * 64 * 16;
    const bf16x8 n0 = *(const bf16x8*)(bbase + nx + jcol);
    const bf16x8 n1 = *(const bf16x8*)(bbase + nx + 32 * 16 + jcol);
    const f32x16 s0 = __builtin_amdgcn_mfma_f32_32x32x16_bf16(afrag, b0, zacc, 0, 0, 0);
    const f32x16 s1 = __builtin_amdgcn_mfma_f32_32x32x16_bf16(afrag, b1, zacc, 0, 0, 0);
    float cm0 = s0[0], cm1 = s1[0];
#pragma unroll
    for (int r = 1; r < 16; ++r) { cm0 = fminf(cm0, s0[r]); cm1 = fminf(cm1, s1[r]); }
#pragma unroll
    for (int r = 0; r < 16; ++r) rmin[r] = fminf(rmin[r], fminf(s0[r], s1[r]));
    cm0 = fminf(cm0, __shfl_xor(cm0, 32, 64));   // join the two row-halves
    cm1 = fminf(cm1, __shfl_xor(cm1, 32, 64));
    if (half == 0) {
      clds[w * kJSL + jt * 64 + l31] = cm0;
      clds[w * kJSL + jt * 64 + 32 + l31] = cm1;
    }
    b0 = n0; b1 = n1;
  }

  // Slice-partial row-mins: butterfly across the 32 lanes of each half.
#pragma unroll
  for (int st = 1; st < 32; st <<= 1) {
#pragma unroll
    for (int r = 0; r < 16; ++r)
      rmin[r] = fminf(rmin[r], __shfl_xor(rmin[r], st, 64));
  }
  if (l31 == 0) {   // lanes 0 and 32: each holds its half's 16 row-mins
    float* rp = rowpart + ((size_t)slice * kB + cloud) * kN + chunk * 128 + w * 32;
#pragma unroll
    for (int r = 0; r < 16; ++r) {
      const int row = (r & 3) + 8 * (r >> 2) + 4 * half;
      rp[row] = rmin[r];
    }
  }

  __syncthreads();
  for (int j = t; j < kJSL; j += 256) {
    const float m = fminf(fminf(clds[j], clds[kJSL + j]),
                          fminf(clds[2 * kJSL + j], clds[3 * kJSL + j]));
    colpart[((size_t)cloud * 32 + chunk) * kN + slice * kJSL + j] = m;
  }
}

// Per (cloud, p): min over kJS row-slices + min over 32 col-chunks; sum both,
// block-sum -> atomicAdd.
__global__ __launch_bounds__(256) void cd_reduce(
    const float* __restrict__ colpart, const float* __restrict__ rowpart,
    float* __restrict__ out) {
  const int u = blockIdx.x * 256 + threadIdx.x;   // 0..kPlane-1
  const int cloud = u >> 12, p = u & (kN - 1);
  float rm = 1e30f;
#pragma unroll
  for (int s2 = 0; s2 < kJS; ++s2)
    rm = fminf(rm, rowpart[((size_t)s2 * kB + cloud) * kN + p]);
  const float* cp = colpart + (size_t)cloud * 32 * kN + p;
  float cm = 1e30f;
#pragma unroll 8
  for (int c = 0; c < 32; ++c) cm = fminf(cm, cp[(size_t)c * kN]);
  float s = rm + cm;
  for (int o = 32; o > 0; o >>= 1) s += __shfl_down(s, o, 64);
  __shared__ float wsum[4];
  const int lane = threadIdx.x & 63, wv = threadIdx.x >> 6;
  if (lane == 0) wsum[wv] = s;
  __syncthreads();
  if (threadIdx.x == 0)
    atomicAdd(out, (wsum[0] + wsum[1] + wsum[2] + wsum[3]) * kScale);
}

// ---------- fallback (small ws): R5-style pk_fma direct kernel ----------
template <int KX>
__global__ __launch_bounds__(256) void chamfer_direct(
    const float* __restrict__ pred, const float* __restrict__ targ,
    float* __restrict__ out) {
  __shared__ float4 tA[128], tB[128];
  const int t = threadIdx.x;
  const int xb = blockIdx.x, b = blockIdx.y, dir = blockIdx.z;
  const float* __restrict__ X = dir ? targ : pred;
  const float* __restrict__ Y = dir ? pred : targ;
  float2 xx2[KX], xy2[KX], xz2[KX];
  float x2[KX], mn[KX];
  const int ibase = b * kN + xb * (256 * KX) + t;
#pragma unroll
  for (int k = 0; k < KX; ++k) {
    const int i = ibase + k * 256;
    const float a = X[3 * i], c = X[3 * i + 1], d = X[3 * i + 2];
    x2[k] = fmaf(a, a, fmaf(c, c, d * d));
    xx2[k] = make_float2(-2.0f * a, -2.0f * a);
    xy2[k] = make_float2(-2.0f * c, -2.0f * c);
    xz2[k] = make_float2(-2.0f * d, -2.0f * d);
    mn[k] = 1e30f;
  }
  for (int t0 = 0; t0 < kN; t0 += 256) {
    __syncthreads();
    if (t < 128) {
      const int j0 = 3 * (b * kN + t0 + 2 * t);
      const float a0 = Y[j0], c0 = Y[j0 + 1], d0 = Y[j0 + 2];
      const float a1 = Y[j0 + 3], c1 = Y[j0 + 4], d1 = Y[j0 + 5];
      tA[t] = make_float4(a0, a1, c0, c1);
      tB[t] = make_float4(d0, d1, fmaf(a0, a0, fmaf(c0, c0, d0 * d0)),
                          fmaf(a1, a1, fmaf(c1, c1, d1 * d1)));
    }
    __syncthreads();
    for (int jj = 0; jj < 128; ++jj) {
      const float4 qa = tA[jj], qb = tB[jj];
      const float2 qx = make_float2(qa.x, qa.y), qy = make_float2(qa.z, qa.w);
      const float2 qz = make_float2(qb.x, qb.y), qw = make_float2(qb.z, qb.w);
#pragma unroll
      for (int k = 0; k < KX; ++k) {
        float2 acc;
        asm("v_pk_fma_f32 %0, %1, %2, %3\n\t"
            "v_pk_fma_f32 %0, %4, %5, %0\n\t"
            "v_pk_fma_f32 %0, %6, %7, %0"
            : "=&v"(acc)
            : "v"(xz2[k]), "v"(qz), "v"(qw), "v"(xy2[k]), "v"(qy),
              "v"(xx2[k]), "v"(qx));
        asm("v_min3_f32 %0, %0, %1, %2" : "+v"(mn[k]) : "v"(acc.x), "v"(acc.y));
      }
    }
  }
  float s = 0.0f;
#pragma unroll
  for (int k = 0; k < KX; ++k) s += x2[k] + mn[k];
  for (int o = 32; o > 0; o >>= 1) s += __shfl_down(s, o, 64);
  __shared__ float wsum[4];
  const int lane = t & 63, wv = t >> 6;
  if (lane == 0) wsum[wv] = s;
  __syncthreads();
  if (t == 0)
    atomicAdd(out, (wsum[0] + wsum[1] + wsum[2] + wsum[3]) * kScale);
}

}  // namespace

extern "C" void kernel_launch(void* const* d_in, const int* in_sizes, int n_in,
                              void* d_out, int out_size, void* d_ws,
                              size_t ws_size, hipStream_t stream) {
  const float* pred = (const float*)d_in[0];
  const float* targ = (const float*)d_in[1];
  float* out = (float*)d_out;

  const size_t needA = (size_t)kPlane * 16 * sizeof(u16);        // 2 MB
  const size_t needCol = (size_t)kB * 32 * kN * sizeof(float);   // 8 MB
  const size_t needRow = (size_t)kJS * kPlane * sizeof(float);   // 1 MB
  if (ws_size >= 2 * needA + needCol + needRow) {                // 13 MB
    u16* Ab = (u16*)d_ws;
    u16* Bb = (u16*)((char*)d_ws + needA);
    float* colpart = (float*)((char*)d_ws + 2 * needA);
    float* rowpart = (float*)((char*)d_ws + 2 * needA + needCol);
    cd_prep<<<dim3(kPlane / 256), 256, 0, stream>>>(pred, targ, Ab, Bb, out);
    cd_mfma<<<dim3(32, kB, kJS), 256, 0, stream>>>(Ab, Bb, colpart, rowpart);
    cd_reduce<<<dim3(kPlane / 256), 256, 0, stream>>>(colpart, rowpart, out);
  } else {
    init_out<<<dim3(1), dim3(1), 0, stream>>>(out);
    constexpr int KX = 8;
    dim3 grid(kN / (256 * KX), kB, 2);
    chamfer_direct<KX><<<grid, 256, 0, stream>>>(pred, targ, out);
  }
}